// Round 15
// baseline (118.626 us; speedup 1.0000x reference)
//
#include <hip/hip_runtime.h>
#include <hip/hip_fp16.h>

#define PTAB_STRIDE 64   // halves per row = 128 B

typedef float    f32x4 __attribute__((ext_vector_type(4)));
typedef _Float16 half8 __attribute__((ext_vector_type(8)));
typedef _Float16 h2    __attribute__((ext_vector_type(2)));

__device__ __forceinline__ h2 u2h2(unsigned int u) {
    union { unsigned int u; h2 h; } c; c.u = u; return c.h;
}

__device__ __forceinline__ float fdot2x(h2 a, h2 b, float c) {
#if __has_builtin(__builtin_amdgcn_fdot2)
    return __builtin_amdgcn_fdot2(a, b, c, false);
#else
    return c + (float)a[0] * (float)b[0] + (float)a[1] * (float)b[1];
#endif
}

__device__ __forceinline__ float clamp9(float a) {
#if __has_builtin(__builtin_amdgcn_fmed3f)
    return __builtin_amdgcn_fmed3f(a, -9.f, 9.f);
#else
    return fminf(9.f, fmaxf(-9.f, a));
#endif
}

// ---------------------------------------------------------------------------
// Kernel 0: pack B-fragments (W^T, fp16, zero-padded to K=320 x N=64) in the
// exact mfma_f32_16x16x32_f16 per-lane layout, + fused bias table.
// ---------------------------------------------------------------------------
__global__ __launch_bounds__(64) void prep_kernel(
    const float* __restrict__ Wih, const float* __restrict__ bih,
    const float* __restrict__ bhh, __half* __restrict__ Bfrag,
    float* __restrict__ bias64)
{
    const int lane = threadIdx.x;
    const int st   = blockIdx.x;
    if (st == 40) {
        if (lane < 64) bias64[lane] = (lane < 50) ? bih[lane] + bhh[lane] : 0.f;
        return;
    }
    const int s  = st >> 2, t = st & 3;
    const int n  = 16 * t + (lane & 15);
    const int kb = lane >> 4;
    half8 v;
    #pragma unroll
    for (int j = 0; j < 8; ++j) {
        const int k = 32 * s + 8 * kb + j;
        float w = 0.f;
        if (n < 50 && k < 300) w = Wih[n * 300 + k];
        v[j] = (_Float16)w;
    }
    *reinterpret_cast<half8*>(Bfrag + ((size_t)st * 64 + lane) * 8) = v;
}

// ---------------------------------------------------------------------------
// Phase 1: ptab[v][h] = fp16( dot(emb[v,:], W_ih[h,:]) + b_ih + b_hh )
// One wave per 16 vocab rows, 4 N-tile accumulators, 40 MFMAs. (proven r8)
// ---------------------------------------------------------------------------
__global__ __launch_bounds__(64) void ptab_mfma(
    const float* __restrict__ emb, const __half* __restrict__ Bfrag,
    const float* __restrict__ bias64, __half* __restrict__ ptab)
{
    const int lane = threadIdx.x;
    const int v0   = blockIdx.x * 16;
    const int m    = lane & 15;
    const int kb   = lane >> 4;
    const float* Erow = emb + (size_t)(v0 + m) * 300;
    const half8* BF   = reinterpret_cast<const half8*>(Bfrag);

    f32x4 acc[4];
    #pragma unroll
    for (int t = 0; t < 4; ++t) acc[t] = (f32x4){0.f, 0.f, 0.f, 0.f};

    #pragma unroll
    for (int s = 0; s < 9; ++s) {
        const int k0 = 32 * s + 8 * kb;
        float4 p0 = *(const float4*)(Erow + k0);
        float4 p1 = *(const float4*)(Erow + k0 + 4);
        half8 a;
        a[0] = (_Float16)p0.x; a[1] = (_Float16)p0.y;
        a[2] = (_Float16)p0.z; a[3] = (_Float16)p0.w;
        a[4] = (_Float16)p1.x; a[5] = (_Float16)p1.y;
        a[6] = (_Float16)p1.z; a[7] = (_Float16)p1.w;
        #pragma unroll
        for (int t = 0; t < 4; ++t)
            acc[t] = __builtin_amdgcn_mfma_f32_16x16x32_f16(
                a, BF[(4 * s + t) * 64 + lane], acc[t], 0, 0, 0);
    }
    {   // tail K-step s=9: k = 288..319, valid only k < 300
        half8 a;
        #pragma unroll
        for (int j = 0; j < 8; ++j) {
            const int k = 288 + 8 * kb + j;
            float e = 0.f;
            if (k < 300) e = Erow[k];
            a[j] = (_Float16)e;
        }
        #pragma unroll
        for (int t = 0; t < 4; ++t)
            acc[t] = __builtin_amdgcn_mfma_f32_16x16x32_f16(
                a, BF[(36 + t) * 64 + lane], acc[t], 0, 0, 0);
    }

    const int nn = lane & 15;
    #pragma unroll
    for (int t = 0; t < 4; ++t) {
        const float bt = bias64[16 * t + nn];
        #pragma unroll
        for (int r = 0; r < 4; ++r)
            ptab[(size_t)(v0 + 4 * kb + r) * PTAB_STRIDE + 16 * t + nn] =
                (__half)(acc[t][r] + bt);
    }
}

// ---------------------------------------------------------------------------
// Phase 2: recurrence + head. 128 blocks x 128 threads: 2 waves per block,
// each wave one independent sequence (still 256 parallel waves, 2/CU).
// __launch_bounds__(128, 2) is the r6-proven allocator recipe that actually
// yields ~120 VGPRs — the point of this round: r8-r14 all ran with VGPR=32-48,
// i.e. the 25 W_hh dwords lived in scratch and were re-fetched EVERY step
// (~150 cyc of the 425-cyc step). With W resident the step is
// ds_write+7 reads (~180) + dots (~30) + tanh (~50).
// Per-wave-private stok/hbuf; no barriers (same-wave DS ordering).
// ---------------------------------------------------------------------------
__global__ __launch_bounds__(128, 2) void rnn_kernel(
    const int* __restrict__ tokens, const __half* __restrict__ ptab,
    const float* __restrict__ Whh,
    const float* __restrict__ Wfc, const float* __restrict__ bfc,
    float* __restrict__ out)
{
    __shared__ int stok[2][544];
    __shared__ __align__(16) _Float16 hbuf[2][64];
    const int lane = threadIdx.x & 63;
    const int wid  = threadIdx.x >> 6;
    const int b    = blockIdx.x * 2 + wid;
    const int hc   = lane < 50 ? lane : 49;

    int* st = stok[wid];
    _Float16* hb = hbuf[wid];

    #pragma unroll
    for (int k = 0; k < 8; ++k)
        st[lane + 64 * k] = tokens[b * 512 + lane + 64 * k];
    if (lane < 32) st[512 + lane] = 0;       // pad: token 0 -> valid row
    // wave-private LDS: in-wave DS ordering suffices, no barrier.

    // W_hh row for this lane: 25 packed fp16 pairs.
    unsigned int wh_u[25];
    #pragma unroll
    for (int j = 0; j < 25; ++j) {
        float2 w2 = *(const float2*)(Whh + hc * 50 + 2 * j);
        union { h2 h; unsigned int u; } c;
        c.h = (h2){(_Float16)w2.x, (_Float16)w2.y};
        wh_u[j] = c.u;
    }

    float h = 0.f;

#define GA(T) ptab[(size_t)(T) * PTAB_STRIDE + lane]

    __half x0 = GA(st[0]), x1 = GA(st[1]), x2 = GA(st[2]), x3 = GA(st[3]);
    __half x4 = GA(st[4]), x5 = GA(st[5]), x6 = GA(st[6]), x7 = GA(st[7]);
    int k0 = st[8],  k1 = st[9],  k2 = st[10], k3 = st[11];
    int k4 = st[12], k5 = st[13], k6 = st[14], k7 = st[15];

#define SL(Q, i) __builtin_shufflevector(Q, Q, 2*(i), 2*(i)+1)
#define WH(j) u2h2(wh_u[j])

#define RNN_STEP(XV)                                                         \
    {                                                                        \
        hb[lane] = (_Float16)h;            /* ds_write_b16, in-order */      \
        const half8* H8 = (const half8*)hb;                                  \
        half8 q0 = H8[0], q1 = H8[1], q2 = H8[2];                            \
        half8 q3 = H8[3], q4 = H8[4], q5 = H8[5];                            \
        h2 q6 = *(const h2*)(hb + 48);                                       \
        float s0 = 0.f, s1 = 0.f, s2 = 0.f, s3 = 0.f;                        \
        s0 = fdot2x(SL(q0,0), WH(0),  s0); s1 = fdot2x(SL(q0,1), WH(1),  s1);\
        s2 = fdot2x(SL(q0,2), WH(2),  s2); s3 = fdot2x(SL(q0,3), WH(3),  s3);\
        s0 = fdot2x(SL(q1,0), WH(4),  s0); s1 = fdot2x(SL(q1,1), WH(5),  s1);\
        s2 = fdot2x(SL(q1,2), WH(6),  s2); s3 = fdot2x(SL(q1,3), WH(7),  s3);\
        s0 = fdot2x(SL(q2,0), WH(8),  s0); s1 = fdot2x(SL(q2,1), WH(9),  s1);\
        s2 = fdot2x(SL(q2,2), WH(10), s2); s3 = fdot2x(SL(q2,3), WH(11), s3);\
        s0 = fdot2x(SL(q3,0), WH(12), s0); s1 = fdot2x(SL(q3,1), WH(13), s1);\
        s2 = fdot2x(SL(q3,2), WH(14), s2); s3 = fdot2x(SL(q3,3), WH(15), s3);\
        s0 = fdot2x(SL(q4,0), WH(16), s0); s1 = fdot2x(SL(q4,1), WH(17), s1);\
        s2 = fdot2x(SL(q4,2), WH(18), s2); s3 = fdot2x(SL(q4,3), WH(19), s3);\
        s0 = fdot2x(SL(q5,0), WH(20), s0); s1 = fdot2x(SL(q5,1), WH(21), s1);\
        s2 = fdot2x(SL(q5,2), WH(22), s2); s3 = fdot2x(SL(q5,3), WH(23), s3);\
        s0 = fdot2x(q6,       WH(24), s0);                                   \
        float a = ((float)(XV) + (s1 + s3)) + (s0 + s2);                     \
        a = clamp9(a);                                                       \
        float e = __expf(2.f * a);                                           \
        h = fmaf(-2.f, __builtin_amdgcn_rcpf(e + 1.f), 1.f);                 \
    }

    for (int t = 0; t < 512; t += 8) {
        // in-loop pin: spilling wh_u would now cost 25 reloads per iteration
        #pragma unroll
        for (int j = 0; j < 25; ++j) asm volatile("" : "+v"(wh_u[j]));

        __half n0 = GA(k0), n1 = GA(k1), n2 = GA(k2), n3 = GA(k3);
        __half n4 = GA(k4), n5 = GA(k5), n6 = GA(k6), n7 = GA(k7);
        k0 = st[t + 16]; k1 = st[t + 17]; k2 = st[t + 18]; k3 = st[t + 19];
        k4 = st[t + 20]; k5 = st[t + 21]; k6 = st[t + 22]; k7 = st[t + 23];

        RNN_STEP(x0); RNN_STEP(x1); RNN_STEP(x2); RNN_STEP(x3);
        RNN_STEP(x4); RNN_STEP(x5); RNN_STEP(x6); RNN_STEP(x7);

        x0 = n0; x1 = n1; x2 = n2; x3 = n3;
        x4 = n4; x5 = n5; x6 = n6; x7 = n7;
    }
#undef RNN_STEP
#undef SL
#undef WH
#undef GA

    // ---- head: out[b][o] = sum_h h[h] * W_fc[o][h] + b_fc[o] ----
    float hv = (lane < 50) ? h : 0.f;
    #pragma unroll
    for (int o = 0; o < 4; ++o) {
        float w = (lane < 50) ? Wfc[o * 50 + lane] : 0.f;
        float p = hv * w;
        #pragma unroll
        for (int s = 32; s > 0; s >>= 1) p += __shfl_xor(p, s, 64);
        if (lane == 0) out[b * 4 + o] = p + bfc[o];
    }
}

extern "C" void kernel_launch(void* const* d_in, const int* in_sizes, int n_in,
                              void* d_out, int out_size, void* d_ws, size_t ws_size,
                              hipStream_t stream)
{
    const int*   tokens = (const int*)d_in[0];
    const float* emb    = (const float*)d_in[1];
    const float* Wih    = (const float*)d_in[2];
    const float* Whh    = (const float*)d_in[3];
    const float* bih    = (const float*)d_in[4];
    const float* bhh    = (const float*)d_in[5];
    const float* Wfc    = (const float*)d_in[6];
    const float* bfc    = (const float*)d_in[7];

    char* ws = (char*)d_ws;
    __half* ptab   = (__half*)ws;                       // 6,400,000 B
    __half* Bfrag  = (__half*)(ws + 6400000);           //    40,960 B
    float*  bias64 = (float*)(ws + 6440960);            //       256 B
    float*  outp   = (float*)d_out;

    prep_kernel<<<41, 64, 0, stream>>>(Wih, bih, bhh, Bfrag, bias64);
    ptab_mfma<<<3125, 64, 0, stream>>>(emb, Bfrag, bias64, ptab);
    rnn_kernel<<<128, 128, 0, stream>>>(tokens, ptab, Whh, Wfc, bfc, outp);
}

// Round 16
// 108.006 us; speedup vs baseline: 1.0983x; 1.0983x over previous
//
#include <hip/hip_runtime.h>
#include <hip/hip_fp16.h>

#define PTAB_STRIDE 64   // halves per row = 128 B

typedef float    f32x4 __attribute__((ext_vector_type(4)));
typedef _Float16 half8 __attribute__((ext_vector_type(8)));
typedef _Float16 h2    __attribute__((ext_vector_type(2)));

__device__ __forceinline__ h2 u2h2(unsigned int u) {
    union { unsigned int u; h2 h; } c; c.u = u; return c.h;
}

__device__ __forceinline__ float fdot2x(h2 a, h2 b, float c) {
#if __has_builtin(__builtin_amdgcn_fdot2)
    return __builtin_amdgcn_fdot2(a, b, c, false);
#else
    return c + (float)a[0] * (float)b[0] + (float)a[1] * (float)b[1];
#endif
}

__device__ __forceinline__ float clamp9(float a) {
#if __has_builtin(__builtin_amdgcn_fmed3f)
    return __builtin_amdgcn_fmed3f(a, -9.f, 9.f);
#else
    return fminf(9.f, fmaxf(-9.f, a));
#endif
}

// ---------------------------------------------------------------------------
// Kernel 0: pack B-fragments (W^T, fp16, zero-padded to K=320 x N=64) in the
// exact mfma_f32_16x16x32_f16 per-lane layout, + fused bias table.
// ---------------------------------------------------------------------------
__global__ __launch_bounds__(64) void prep_kernel(
    const float* __restrict__ Wih, const float* __restrict__ bih,
    const float* __restrict__ bhh, __half* __restrict__ Bfrag,
    float* __restrict__ bias64)
{
    const int lane = threadIdx.x;
    const int st   = blockIdx.x;
    if (st == 40) {
        if (lane < 64) bias64[lane] = (lane < 50) ? bih[lane] + bhh[lane] : 0.f;
        return;
    }
    const int s  = st >> 2, t = st & 3;
    const int n  = 16 * t + (lane & 15);
    const int kb = lane >> 4;
    half8 v;
    #pragma unroll
    for (int j = 0; j < 8; ++j) {
        const int k = 32 * s + 8 * kb + j;
        float w = 0.f;
        if (n < 50 && k < 300) w = Wih[n * 300 + k];
        v[j] = (_Float16)w;
    }
    *reinterpret_cast<half8*>(Bfrag + ((size_t)st * 64 + lane) * 8) = v;
}

// ---------------------------------------------------------------------------
// Phase 1: ptab[v][h] = fp16( dot(emb[v,:], W_ih[h,:]) + b_ih + b_hh )
// One wave per 16 vocab rows, 4 N-tile accumulators, 40 MFMAs. (proven r8)
// ---------------------------------------------------------------------------
__global__ __launch_bounds__(64) void ptab_mfma(
    const float* __restrict__ emb, const __half* __restrict__ Bfrag,
    const float* __restrict__ bias64, __half* __restrict__ ptab)
{
    const int lane = threadIdx.x;
    const int v0   = blockIdx.x * 16;
    const int m    = lane & 15;
    const int kb   = lane >> 4;
    const float* Erow = emb + (size_t)(v0 + m) * 300;
    const half8* BF   = reinterpret_cast<const half8*>(Bfrag);

    f32x4 acc[4];
    #pragma unroll
    for (int t = 0; t < 4; ++t) acc[t] = (f32x4){0.f, 0.f, 0.f, 0.f};

    #pragma unroll
    for (int s = 0; s < 9; ++s) {
        const int k0 = 32 * s + 8 * kb;
        float4 p0 = *(const float4*)(Erow + k0);
        float4 p1 = *(const float4*)(Erow + k0 + 4);
        half8 a;
        a[0] = (_Float16)p0.x; a[1] = (_Float16)p0.y;
        a[2] = (_Float16)p0.z; a[3] = (_Float16)p0.w;
        a[4] = (_Float16)p1.x; a[5] = (_Float16)p1.y;
        a[6] = (_Float16)p1.z; a[7] = (_Float16)p1.w;
        #pragma unroll
        for (int t = 0; t < 4; ++t)
            acc[t] = __builtin_amdgcn_mfma_f32_16x16x32_f16(
                a, BF[(4 * s + t) * 64 + lane], acc[t], 0, 0, 0);
    }
    {   // tail K-step s=9: k = 288..319, valid only k < 300
        half8 a;
        #pragma unroll
        for (int j = 0; j < 8; ++j) {
            const int k = 288 + 8 * kb + j;
            float e = 0.f;
            if (k < 300) e = Erow[k];
            a[j] = (_Float16)e;
        }
        #pragma unroll
        for (int t = 0; t < 4; ++t)
            acc[t] = __builtin_amdgcn_mfma_f32_16x16x32_f16(
                a, BF[(36 + t) * 64 + lane], acc[t], 0, 0, 0);
    }

    const int nn = lane & 15;
    #pragma unroll
    for (int t = 0; t < 4; ++t) {
        const float bt = bias64[16 * t + nn];
        #pragma unroll
        for (int r = 0; r < 4; ++r)
            ptab[(size_t)(v0 + 4 * kb + r) * PTAB_STRIDE + 16 * t + nn] =
                (__half)(acc[t][r] + bt);
    }
}

// ---------------------------------------------------------------------------
// Phase 2: recurrence + head. One sequence per wave, 256 waves (1/CU).
// r9 LDS-broadcast skeleton, re-budgeted to FIT the allocator's ~64-VGPR
// envelope so nothing spills (r9-r15 all ran at VGPR=32-48 while demanding
// ~85 -> W_hh and transients lived in scratch; every pinning/occupancy trick
// failed to raise the allocation, so this round lowers the demand instead):
//   - no k-ring: token indices re-read from stok at gather-issue time
//     (transient; the 8-step x-prefetch distance absorbs the LDS latency)
//   - h-broadcast reads staged 2 words at a time, interleaved with their
//     dot groups (peak transient 8 dwords instead of 26)
//   - no asm pins
// Demand: 25 W + 8 x + 8 n + ~8 transients + misc ~= 57 VGPRs.
// ---------------------------------------------------------------------------
__global__ __launch_bounds__(64, 1) void rnn_kernel(
    const int* __restrict__ tokens, const __half* __restrict__ ptab,
    const float* __restrict__ Whh,
    const float* __restrict__ Wfc, const float* __restrict__ bfc,
    float* __restrict__ out)
{
    __shared__ int stok[544];
    __shared__ __align__(16) _Float16 hbuf[64];
    const int lane = threadIdx.x;
    const int b    = blockIdx.x;
    const int hc   = lane < 50 ? lane : 49;

    #pragma unroll
    for (int k = 0; k < 8; ++k)
        stok[lane + 64 * k] = tokens[b * 512 + lane + 64 * k];
    if (lane < 32) stok[512 + lane] = 0;     // pad: token 0 -> valid row
    __syncthreads();

    // W_hh row for this lane: 25 packed fp16 pairs (register-resident by
    // design: total demand now fits the allocator's budget).
    unsigned int wh_u[25];
    #pragma unroll
    for (int j = 0; j < 25; ++j) {
        float2 w2 = *(const float2*)(Whh + hc * 50 + 2 * j);
        union { h2 h; unsigned int u; } c;
        c.h = (h2){(_Float16)w2.x, (_Float16)w2.y};
        wh_u[j] = c.u;
    }

    float h = 0.f;

#define GA(T) ptab[(size_t)(T) * PTAB_STRIDE + lane]

    __half x0 = GA(stok[0]), x1 = GA(stok[1]), x2 = GA(stok[2]), x3 = GA(stok[3]);
    __half x4 = GA(stok[4]), x5 = GA(stok[5]), x6 = GA(stok[6]), x7 = GA(stok[7]);

#define SL(Q, i) __builtin_shufflevector(Q, Q, 2*(i), 2*(i)+1)
#define WH(j) u2h2(wh_u[j])

#define RNN_STEP(XV)                                                         \
    {                                                                        \
        hbuf[lane] = (_Float16)h;          /* ds_write_b16, in-order */      \
        const half8* H8 = (const half8*)hbuf;                                \
        half8 q0 = H8[0], q1 = H8[1];                                        \
        float s0 = 0.f, s1 = 0.f, s2 = 0.f, s3 = 0.f;                        \
        s0 = fdot2x(SL(q0,0), WH(0),  s0); s1 = fdot2x(SL(q0,1), WH(1),  s1);\
        s2 = fdot2x(SL(q0,2), WH(2),  s2); s3 = fdot2x(SL(q0,3), WH(3),  s3);\
        s0 = fdot2x(SL(q1,0), WH(4),  s0); s1 = fdot2x(SL(q1,1), WH(5),  s1);\
        s2 = fdot2x(SL(q1,2), WH(6),  s2); s3 = fdot2x(SL(q1,3), WH(7),  s3);\
        half8 q2 = H8[2], q3 = H8[3];                                        \
        s0 = fdot2x(SL(q2,0), WH(8),  s0); s1 = fdot2x(SL(q2,1), WH(9),  s1);\
        s2 = fdot2x(SL(q2,2), WH(10), s2); s3 = fdot2x(SL(q2,3), WH(11), s3);\
        s0 = fdot2x(SL(q3,0), WH(12), s0); s1 = fdot2x(SL(q3,1), WH(13), s1);\
        s2 = fdot2x(SL(q3,2), WH(14), s2); s3 = fdot2x(SL(q3,3), WH(15), s3);\
        half8 q4 = H8[4], q5 = H8[5];                                        \
        h2 q6 = *(const h2*)(hbuf + 48);                                     \
        s0 = fdot2x(SL(q4,0), WH(16), s0); s1 = fdot2x(SL(q4,1), WH(17), s1);\
        s2 = fdot2x(SL(q4,2), WH(18), s2); s3 = fdot2x(SL(q4,3), WH(19), s3);\
        s0 = fdot2x(SL(q5,0), WH(20), s0); s1 = fdot2x(SL(q5,1), WH(21), s1);\
        s2 = fdot2x(SL(q5,2), WH(22), s2); s3 = fdot2x(SL(q5,3), WH(23), s3);\
        s0 = fdot2x(q6,       WH(24), s0);                                   \
        float a = ((float)(XV) + (s1 + s3)) + (s0 + s2);                     \
        a = clamp9(a);                                                       \
        float e = __expf(2.f * a);                                           \
        h = fmaf(-2.f, __builtin_amdgcn_rcpf(e + 1.f), 1.f);                 \
    }

    for (int t = 0; t < 512; t += 8) {
        // token indices read as transients; gathers issued 8 steps ahead
        __half n0 = GA(stok[t + 8]);
        __half n1 = GA(stok[t + 9]);
        __half n2 = GA(stok[t + 10]);
        __half n3 = GA(stok[t + 11]);
        __half n4 = GA(stok[t + 12]);
        __half n5 = GA(stok[t + 13]);
        __half n6 = GA(stok[t + 14]);
        __half n7 = GA(stok[t + 15]);

        RNN_STEP(x0); RNN_STEP(x1); RNN_STEP(x2); RNN_STEP(x3);
        RNN_STEP(x4); RNN_STEP(x5); RNN_STEP(x6); RNN_STEP(x7);

        x0 = n0; x1 = n1; x2 = n2; x3 = n3;
        x4 = n4; x5 = n5; x6 = n6; x7 = n7;
    }
#undef RNN_STEP
#undef SL
#undef WH
#undef GA

    // ---- head: out[b][o] = sum_h h[h] * W_fc[o][h] + b_fc[o] ----
    float hv = (lane < 50) ? h : 0.f;
    #pragma unroll
    for (int o = 0; o < 4; ++o) {
        float w = (lane < 50) ? Wfc[o * 50 + lane] : 0.f;
        float p = hv * w;
        #pragma unroll
        for (int s = 32; s > 0; s >>= 1) p += __shfl_xor(p, s, 64);
        if (lane == 0) out[b * 4 + o] = p + bfc[o];
    }
}

extern "C" void kernel_launch(void* const* d_in, const int* in_sizes, int n_in,
                              void* d_out, int out_size, void* d_ws, size_t ws_size,
                              hipStream_t stream)
{
    const int*   tokens = (const int*)d_in[0];
    const float* emb    = (const float*)d_in[1];
    const float* Wih    = (const float*)d_in[2];
    const float* Whh    = (const float*)d_in[3];
    const float* bih    = (const float*)d_in[4];
    const float* bhh    = (const float*)d_in[5];
    const float* Wfc    = (const float*)d_in[6];
    const float* bfc    = (const float*)d_in[7];

    char* ws = (char*)d_ws;
    __half* ptab   = (__half*)ws;                       // 6,400,000 B
    __half* Bfrag  = (__half*)(ws + 6400000);           //    40,960 B
    float*  bias64 = (float*)(ws + 6440960);            //       256 B
    float*  outp   = (float*)d_out;

    prep_kernel<<<41, 64, 0, stream>>>(Wih, bih, bhh, Bfrag, bias64);
    ptab_mfma<<<3125, 64, 0, stream>>>(emb, Bfrag, bias64, ptab);
    rnn_kernel<<<256, 64, 0, stream>>>(tokens, ptab, Whh, Wfc, bfc, outp);
}